// Round 2
// baseline (163.722 us; speedup 1.0000x reference)
//
#include <hip/hip_runtime.h>
#include <stdint.h>

// Beam-search step for CaptionModel (B=128 beams, V=128000 vocab).
//
// Key identity: the reference's two-stage top-k (per-row top-128, then global
// top-128 over sum[q]+ys) == single global top-128 over (sum[b] + lp[b,v]),
// because any element outside its row's top-128 is dominated by >=128 same-row
// elements (identical sum[b]). Tie order (value desc, then flat (q,c) asc) is
// reproduced exactly by composite key (f32key<<32) | (0xFFFFFFFF - (b*V+v)):
// within a row, order by (value desc, v asc) == (value desc, c asc); across
// rows, smaller b wins ties == smaller q wins. jax.lax.top_k is stable
// (lower index first on ties), so this matches bit-exactly.
//
// Pipeline: 12-bit-key histogram over all 16.4M elements -> threshold bin ->
// collect candidates (>= tbin, ~900 expected) -> single-block two-level
// refine + bitonic sort of <=512 finalists -> scatter outputs.

#define HIST_SIZE 4096
#define CAP2 4096
#define FINCAP 512

__device__ __forceinline__ unsigned f2key(float f) {
  unsigned u = __float_as_uint(f);
  return (u & 0x80000000u) ? ~u : (u | 0x80000000u);
}
__device__ __forceinline__ float key2f(unsigned k) {
  unsigned u = (k & 0x80000000u) ? (k & 0x7fffffffu) : ~k;
  return __uint_as_float(u);
}

extern "C" __global__ void __launch_bounds__(256)
k_hist(const float* __restrict__ logp, const float* __restrict__ bsum,
       const int* __restrict__ tptr, int V, int bs,
       unsigned* __restrict__ ghist) {
  __shared__ unsigned hist[HIST_SIZE];
  for (int i = threadIdx.x; i < HIST_SIZE; i += 256) hist[i] = 0;
  __syncthreads();
  int t = *tptr;
  int rows = (t >= 1) ? bs : 1;
  long long stride = (long long)gridDim.x * 256;
  long long gid = (long long)blockIdx.x * 256 + threadIdx.x;
  if ((V & 3) == 0) {
    int V4 = V >> 2;
    long long total4 = (long long)rows * V4;
    const float4* lp4 = (const float4*)logp;
    for (long long i = gid; i < total4; i += stride) {
      int b = (int)(i / V4);
      int v0 = (int)(i - (long long)b * V4) << 2;
      float4 f = lp4[i];
      float s = bsum[b];
      float x0 = f.x, x1 = f.y, x2 = f.z, x3 = f.w;
      if (v0 + 3 == V - 1) x3 -= 1000.0f;  // EOS penalty (last elem of row)
      atomicAdd(&hist[f2key(s + x0) >> 20], 1u);
      atomicAdd(&hist[f2key(s + x1) >> 20], 1u);
      atomicAdd(&hist[f2key(s + x2) >> 20], 1u);
      atomicAdd(&hist[f2key(s + x3) >> 20], 1u);
    }
  } else {
    long long total = (long long)rows * V;
    for (long long i = gid; i < total; i += stride) {
      int b = (int)(i / V);
      int v = (int)(i - (long long)b * V);
      float x = logp[i];
      if (v == V - 1) x -= 1000.0f;
      atomicAdd(&hist[f2key(bsum[b] + x) >> 20], 1u);
    }
  }
  __syncthreads();
  for (int i = threadIdx.x; i < HIST_SIZE; i += 256) {
    unsigned c = hist[i];
    if (c) atomicAdd(&ghist[i], c);
  }
}

extern "C" __global__ void __launch_bounds__(256)
k_thresh(const unsigned* __restrict__ ghist, int K, int* __restrict__ tbin_out) {
  __shared__ unsigned h[HIST_SIZE];
  __shared__ unsigned seg[256];
  int tid = threadIdx.x;
  for (int i = tid; i < HIST_SIZE; i += 256) h[i] = ghist[i];
  __syncthreads();
  unsigned s = 0;
#pragma unroll
  for (int j = 0; j < HIST_SIZE / 256; ++j) s += h[tid * (HIST_SIZE / 256) + j];
  seg[tid] = s;
  __syncthreads();
  if (tid == 0) {
    unsigned acc = 0;
    int tbin = 0;
    bool found = false;
    for (int sg = 255; sg >= 0 && !found; --sg) {
      if (acc + seg[sg] >= (unsigned)K) {
        int lo = sg * (HIST_SIZE / 256);
        for (int bn = lo + HIST_SIZE / 256 - 1; bn >= lo; --bn) {
          if (acc + h[bn] >= (unsigned)K) { tbin = bn; found = true; break; }
          acc += h[bn];
        }
      } else {
        acc += seg[sg];
      }
    }
    *tbin_out = tbin;
  }
}

extern "C" __global__ void __launch_bounds__(256)
k_collect(const float* __restrict__ logp, const float* __restrict__ bsum,
          const int* __restrict__ tptr, int V, int bs,
          const int* __restrict__ tbin_p,
          unsigned long long* __restrict__ cand, int* __restrict__ cnt) {
  int t = *tptr;
  int rows = (t >= 1) ? bs : 1;
  int tbin = *tbin_p;
  long long stride = (long long)gridDim.x * 256;
  long long gid = (long long)blockIdx.x * 256 + threadIdx.x;
  if ((V & 3) == 0) {
    int V4 = V >> 2;
    long long total4 = (long long)rows * V4;
    const float4* lp4 = (const float4*)logp;
    for (long long i = gid; i < total4; i += stride) {
      int b = (int)(i / V4);
      int v0 = (int)(i - (long long)b * V4) << 2;
      float4 f = lp4[i];
      float s = bsum[b];
      float xs[4] = {f.x, f.y, f.z, f.w};
      if (v0 + 3 == V - 1) xs[3] -= 1000.0f;
#pragma unroll
      for (int j = 0; j < 4; ++j) {
        unsigned key = f2key(s + xs[j]);
        if ((int)(key >> 20) >= tbin) {
          int pos = atomicAdd(cnt, 1);
          if (pos < CAP2) {
            unsigned flat = (unsigned)b * (unsigned)V + (unsigned)(v0 + j);
            cand[pos] = ((unsigned long long)key << 32) | (0xFFFFFFFFu - flat);
          }
        }
      }
    }
  } else {
    long long total = (long long)rows * V;
    for (long long i = gid; i < total; i += stride) {
      int b = (int)(i / V);
      int v = (int)(i - (long long)b * V);
      float x = logp[i];
      if (v == V - 1) x -= 1000.0f;
      unsigned key = f2key(bsum[b] + x);
      if ((int)(key >> 20) >= tbin) {
        int pos = atomicAdd(cnt, 1);
        if (pos < CAP2) {
          unsigned flat = (unsigned)b * (unsigned)V + (unsigned)v;
          cand[pos] = ((unsigned long long)key << 32) | (0xFFFFFFFFu - flat);
        }
      }
    }
  }
}

// Single block. Two-level refine: candidates with bin > tbin number < K by
// construction of tbin; among bin == tbin, histogram key bits [19:8] and
// re-threshold -> finalists <= ~K + collisions (24-bit prefix collisions are
// rare for random data). Exact bitonic sort of <=512 finalists.
extern "C" __global__ void __launch_bounds__(256)
k_select(const float* __restrict__ logp, const int* __restrict__ cntp,
         const unsigned long long* __restrict__ cand_g, int V, int K,
         const int* __restrict__ tbin_p,
         float* __restrict__ out_sum, int* __restrict__ qsel,
         int* __restrict__ tok, float* __restrict__ loc) {
  __shared__ unsigned hist2[HIST_SIZE];
  __shared__ unsigned seg[256];
  __shared__ unsigned long long fin[FINCAP];
  __shared__ int sh_cnt_hi, sh_nfin, sh_tbin2;
  int tid = threadIdx.x;
  int n = *cntp;
  if (n > CAP2) n = CAP2;
  int tbin = *tbin_p;
  for (int i = tid; i < HIST_SIZE; i += 256) hist2[i] = 0;
  if (tid == 0) { sh_cnt_hi = 0; sh_nfin = 0; sh_tbin2 = 0; }
  __syncthreads();
  for (int i = tid; i < n; i += 256) {
    unsigned key = (unsigned)(cand_g[i] >> 32);
    int bin = (int)(key >> 20);
    if (bin > tbin) atomicAdd(&sh_cnt_hi, 1);
    else atomicAdd(&hist2[(key >> 8) & 0xFFFu], 1u);
  }
  __syncthreads();
  int cnt_hi = sh_cnt_hi;            // < K by construction
  unsigned s = 0;
#pragma unroll
  for (int j = 0; j < HIST_SIZE / 256; ++j) s += hist2[tid * (HIST_SIZE / 256) + j];
  seg[tid] = s;
  __syncthreads();
  if (tid == 0) {
    unsigned need = (unsigned)(K - cnt_hi);
    unsigned acc = 0;
    int tb2 = 0;
    bool found = false;
    for (int sg = 255; sg >= 0 && !found; --sg) {
      if (acc + seg[sg] >= need) {
        int lo = sg * (HIST_SIZE / 256);
        for (int bn = lo + HIST_SIZE / 256 - 1; bn >= lo; --bn) {
          if (acc + hist2[bn] >= need) { tb2 = bn; found = true; break; }
          acc += hist2[bn];
        }
      } else {
        acc += seg[sg];
      }
    }
    sh_tbin2 = tb2;
  }
  __syncthreads();
  int tbin2 = sh_tbin2;
  for (int i = tid; i < n; i += 256) {
    unsigned long long c = cand_g[i];
    unsigned key = (unsigned)(c >> 32);
    int bin = (int)(key >> 20);
    bool keep = (bin > tbin) || ((int)((key >> 8) & 0xFFFu) >= tbin2);
    if (keep) {
      int pos = atomicAdd(&sh_nfin, 1);
      if (pos < FINCAP) fin[pos] = c;
    }
  }
  __syncthreads();
  int nf = sh_nfin;
  if (nf > FINCAP) nf = FINCAP;
  int m = 2;
  while (m < nf) m <<= 1;            // <= FINCAP (power of two)
  for (int i = nf + tid; i < m; i += 256) fin[i] = 0ull;
  __syncthreads();
  for (int k2 = 2; k2 <= m; k2 <<= 1) {
    for (int j = k2 >> 1; j > 0; j >>= 1) {
      for (int i = tid; i < m; i += 256) {
        int l = i ^ j;
        if (l > i) {
          unsigned long long ai = fin[i], al = fin[l];
          bool desc = ((i & k2) == 0);
          if (desc ? (ai < al) : (ai > al)) { fin[i] = al; fin[l] = ai; }
        }
      }
      __syncthreads();
    }
  }
  if (tid < K) {
    unsigned long long c = fin[tid];
    unsigned key = (unsigned)(c >> 32);
    unsigned flat = 0xFFFFFFFFu - (unsigned)(c & 0xFFFFFFFFull);
    int b = (int)(flat / (unsigned)V);
    int v = (int)(flat - (unsigned)b * (unsigned)V);
    out_sum[tid] = key2f(key);       // bit-exact sum[b] + penalized lp
    qsel[tid] = b;
    tok[tid] = v;
    float x = logp[(size_t)b * V + v];
    if (v == V - 1) x -= 1000.0f;
    loc[tid] = x;                    // exact ys value
  }
}

extern "C" __global__ void __launch_bounds__(256)
k_scatter(const int* __restrict__ beam_seq, const float* __restrict__ beam_lp,
          const float4* __restrict__ h4, const float4* __restrict__ c4,
          const int* __restrict__ tptr, const int* __restrict__ qsel,
          const int* __restrict__ tok, const float* __restrict__ loc,
          int T, int B, int LBH4, int H4,
          float* __restrict__ out, float4* __restrict__ outh4,
          float4* __restrict__ outc4) {
  int t = *tptr;
  size_t n_seq = (size_t)T * B;
  size_t scalar_items = 2 * n_seq;
  size_t total = scalar_items + 2 * (size_t)LBH4;
  size_t stride = (size_t)gridDim.x * 256;
  for (size_t j = (size_t)blockIdx.x * 256 + threadIdx.x; j < total; j += stride) {
    if (j < n_seq) {
      int ss = (int)(j / B), b = (int)(j % B);
      int val;
      if (ss < t)       val = beam_seq[(size_t)ss * B + qsel[b]];
      else if (ss == t) val = tok[b];
      else              val = beam_seq[j];
      out[j] = (float)val;           // token ids < 2^24: exact in f32
    } else if (j < scalar_items) {
      size_t jj = j - n_seq;
      int ss = (int)(jj / B), b = (int)(jj % B);
      float v;
      if (ss < t)       v = beam_lp[(size_t)ss * B + qsel[b]];
      else if (ss == t) v = loc[b];
      else              v = beam_lp[jj];
      out[j] = v;
    } else {
      size_t jj = j - scalar_items;
      bool is_c = jj >= (size_t)LBH4;
      size_t k = is_c ? jj - (size_t)LBH4 : jj;
      int row = (int)(k / H4);
      int h = (int)(k - (size_t)row * H4);
      int b = row % B;               // row = l*B + b
      size_t src = (size_t)(row - b + qsel[b]) * H4 + h;
      if (is_c) outc4[k] = c4[src];
      else      outh4[k] = h4[src];
    }
  }
}

extern "C" void kernel_launch(void* const* d_in, const int* in_sizes, int n_in,
                              void* d_out, int out_size, void* d_ws, size_t ws_size,
                              hipStream_t stream) {
  const float* logp = (const float*)d_in[0];
  const int* beam_seq = (const int*)d_in[1];
  const float* beam_lp = (const float*)d_in[2];
  const float* bsum = (const float*)d_in[3];
  const float* st_h = (const float*)d_in[4];
  const float* st_c = (const float*)d_in[5];
  const int* tptr = (const int*)d_in[6];

  int B = in_sizes[3];                 // 128
  int V = in_sizes[0] / B;             // 128000
  int T = in_sizes[1] / B;             // 128
  int LBH = in_sizes[4];               // L*B*H = 262144
  int LH = LBH / B;                    // L*H = 2048
  int bs = (out_size - 2 * in_sizes[1]) / (1 + 2 * LH);  // beam_size = 128
  int H = 1024;                        // fixed for this problem
  int H4 = H / 4, LBH4 = LBH / 4;

  char* ws = (char*)d_ws;
  unsigned* ghist = (unsigned*)ws;                               // 16384 B
  int* cnt = (int*)(ws + 16384);                                 // 4 B
  int* tbin = (int*)(ws + 16388);                                // 4 B
  unsigned long long* cand = (unsigned long long*)(ws + 16392);  // CAP2*8 B (8-aligned)
  int* qsel = (int*)(ws + 16392 + CAP2 * 8);
  int* tok = qsel + bs;
  float* loc = (float*)(tok + bs);

  float* out = (float*)d_out;
  size_t n_seq = (size_t)T * B;
  float* out_sum = out + 2 * n_seq;
  float4* outh4 = (float4*)(out + 2 * n_seq + bs);   // offset 32896 floats: 16B-aligned
  float4* outc4 = outh4 + LBH4;

  hipMemsetAsync(d_ws, 0, 16392, stream);
  k_hist<<<1024, 256, 0, stream>>>(logp, bsum, tptr, V, bs, ghist);
  k_thresh<<<1, 256, 0, stream>>>(ghist, bs, tbin);
  k_collect<<<1024, 256, 0, stream>>>(logp, bsum, tptr, V, bs, tbin, cand, cnt);
  k_select<<<1, 256, 0, stream>>>(logp, cnt, cand, V, bs, tbin, out_sum, qsel, tok, loc);

  size_t total = 2 * n_seq + 2 * (size_t)LBH4;
  int blocks = (int)((total + 255) / 256);
  k_scatter<<<blocks, 256, 0, stream>>>(beam_seq, beam_lp,
                                        (const float4*)st_h, (const float4*)st_c,
                                        tptr, qsel, tok, loc,
                                        T, B, LBH4, H4, out, outh4, outc4);
}

// Round 4
// 157.718 us; speedup vs baseline: 1.0381x; 1.0381x over previous
//
#include <hip/hip_runtime.h>
#include <stdint.h>

// Beam-search step for CaptionModel (B=128 beams, V=128000 vocab).
//
// Identity (verified bit-exact, round 2 absmax=0.0): reference's two-stage
// top-k == single global top-128 over (sum[b] + lp[b,v]) with composite key
// (f32key<<32) | (0xFFFFFFFF - (b*V+v)) reproducing jax's tie order.
//
// Structure (single full read, no per-element LDS atomics in the hot pass):
//  k_sample : read 1MB sample (1/16), 4096-bin histogram of top-12 key bits
//  k_pick   : speculative threshold bin t_lo = sampled suffix-count >= 128
//             (=> ~2-5K actual candidates; never < 128, never > 32K)
//  k_main   : ONE full 65.5MB streaming pass; collect cand >= t_lo via
//             per-block LDS buffer, one global atomic per block
//  k_select : exact top-128 of candidates (two-level radix refine with
//             parallel suffix-scan + bitonic sort of <=512 finalists)
//  k_scatter: gather/write outputs (float4 on state h/c)

#define SHIST 4096
#define CAP 32768
#define LCAP 256
#define FINCAP 512

typedef unsigned long long u64;

__device__ __forceinline__ unsigned f2key(float f) {
  unsigned u = __float_as_uint(f);
  return (u & 0x80000000u) ? ~u : (u | 0x80000000u);
}
__device__ __forceinline__ float key2f(unsigned k) {
  unsigned u = (k & 0x80000000u) ? (k & 0x7fffffffu) : ~k;
  return __uint_as_float(u);
}

// Parallel suffix-scan threshold: find bin such that count(bins > bin) < target
// <= count(bins >= bin). Outputs via shared scalars. All 256 threads call.
__device__ __forceinline__ void suffix_thresh(unsigned* h /*SHIST*/, unsigned* seg /*256*/,
                                              unsigned target, int* sh_bin,
                                              unsigned* sh_above, int tid) {
  unsigned s = 0;
#pragma unroll
  for (int j = 0; j < SHIST / 256; ++j) s += h[tid * (SHIST / 256) + j];
  seg[tid] = s;
  __syncthreads();
  for (int off = 1; off < 256; off <<= 1) {   // inclusive suffix sums
    unsigned add = (tid + off < 256) ? seg[tid + off] : 0;
    __syncthreads();
    seg[tid] += add;
    __syncthreads();
  }
  unsigned excl = (tid + 1 < 256) ? seg[tid + 1] : 0;  // count above my segment
  unsigned incl = seg[tid];
  if (tid == 0) { *sh_bin = 0; *sh_above = 0; }        // default: total < target
  __syncthreads();
  if (excl < target && incl >= target) {               // unique crossing thread
    unsigned acc = excl;
    int lo = tid * (SHIST / 256);
    for (int bn = lo + SHIST / 256 - 1; bn >= lo; --bn) {
      unsigned hb = h[bn];
      if (acc + hb >= target) { *sh_bin = bn; *sh_above = acc; break; }
      acc += hb;
    }
  }
  __syncthreads();
}

extern "C" __global__ void __launch_bounds__(256)
k_sample(const float* __restrict__ logp, const float* __restrict__ bsum,
         const int* __restrict__ tptr, int V, int bs,
         unsigned* __restrict__ shist) {
  __shared__ unsigned hist[SHIST];
  for (int i = threadIdx.x; i < SHIST; i += 256) hist[i] = 0;
  __syncthreads();
  int t = *tptr;
  int rows = (t >= 1) ? bs : 1;
  long long total = (long long)rows * V;
  long long step = total / gridDim.x;           // contiguous chunk per block
  long long start = (long long)blockIdx.x * step;
  int tid = threadIdx.x;
#pragma unroll 4
  for (int j = 0; j < 16; ++j) {                // 4096 elems per block, coalesced
    long long idx = start + (long long)j * 256 + tid;
    if (idx < total) {
      int b = (int)(idx / V);
      int v = (int)(idx - (long long)b * V);
      float x = logp[idx];
      if (v == V - 1) x -= 1000.0f;
      atomicAdd(&hist[f2key(bsum[b] + x) >> 20], 1u);
    }
  }
  __syncthreads();
  for (int i = tid; i < SHIST; i += 256) {
    unsigned c = hist[i];
    if (c) atomicAdd(&shist[i], c);
  }
}

extern "C" __global__ void __launch_bounds__(256)
k_pick(const unsigned* __restrict__ shist, int K, unsigned* __restrict__ tlo_key) {
  __shared__ unsigned h[SHIST];
  __shared__ unsigned seg[256];
  __shared__ int sh_bin;
  __shared__ unsigned sh_above;
  int tid = threadIdx.x;
  for (int i = tid; i < SHIST; i += 256) h[i] = shist[i];
  __syncthreads();
  suffix_thresh(h, seg, (unsigned)K, &sh_bin, &sh_above, tid);
  if (tid == 0) *tlo_key = (unsigned)sh_bin << 20;
}

extern "C" __global__ void __launch_bounds__(256)
k_main(const float* __restrict__ logp, const float* __restrict__ bsum,
       const int* __restrict__ tptr, int V, int bs,
       const unsigned* __restrict__ tlo_p,
       u64* __restrict__ cand, int* __restrict__ cnt) {
  __shared__ u64 lbuf[LCAP];
  __shared__ int lcnt, lbase;
  int tid = threadIdx.x;
  if (tid == 0) lcnt = 0;
  __syncthreads();
  int t = *tptr;
  int rows = (t >= 1) ? bs : 1;
  unsigned tlo = *tlo_p;
  if ((V & 3) == 0) {
    unsigned V4 = (unsigned)V >> 2;
    unsigned total4 = (unsigned)rows * V4;
    unsigned stride = gridDim.x * 256;
    const float4* lp4 = (const float4*)logp;
    for (unsigned i = blockIdx.x * 256 + tid; i < total4; i += stride) {
      unsigned b = i / V4;
      unsigned v0 = (i - b * V4) << 2;
      float4 f = lp4[i];
      float s = bsum[b];
      float xs[4] = {f.x, f.y, f.z, f.w};
      if (v0 + 3 == (unsigned)V - 1) xs[3] -= 1000.0f;   // EOS penalty
#pragma unroll
      for (int j = 0; j < 4; ++j) {
        unsigned key = f2key(s + xs[j]);
        if (key >= tlo) {
          int p = atomicAdd(&lcnt, 1);
          if (p < LCAP) {
            unsigned flat = b * (unsigned)V + v0 + j;
            lbuf[p] = ((u64)key << 32) | (0xFFFFFFFFu - flat);
          }
        }
      }
    }
  } else {
    long long total = (long long)rows * V;
    long long stride = (long long)gridDim.x * 256;
    for (long long i = (long long)blockIdx.x * 256 + tid; i < total; i += stride) {
      int b = (int)(i / V);
      int v = (int)(i - (long long)b * V);
      float x = logp[i];
      if (v == V - 1) x -= 1000.0f;
      unsigned key = f2key(bsum[b] + x);
      if (key >= tlo) {
        int p = atomicAdd(&lcnt, 1);
        if (p < LCAP) {
          unsigned flat = (unsigned)b * (unsigned)V + (unsigned)v;
          lbuf[p] = ((u64)key << 32) | (0xFFFFFFFFu - flat);
        }
      }
    }
  }
  __syncthreads();
  int n = lcnt < LCAP ? lcnt : LCAP;
  if (tid == 0) lbase = atomicAdd(cnt, n);
  __syncthreads();
  int base = lbase;
  for (int i = tid; i < n; i += 256) {
    int g = base + i;
    if (g < CAP) cand[g] = lbuf[i];
  }
}

extern "C" __global__ void __launch_bounds__(256)
k_select(const float* __restrict__ logp, const int* __restrict__ cntp,
         const u64* __restrict__ cand_g, int V, int K,
         float* __restrict__ out_sum, int* __restrict__ qsel,
         int* __restrict__ tok, float* __restrict__ loc) {
  __shared__ unsigned hist[SHIST];
  __shared__ unsigned seg[256];
  __shared__ u64 fin[FINCAP];
  __shared__ int sh_bin, sh_nfin;
  __shared__ unsigned sh_above;
  int tid = threadIdx.x;
  int n = *cntp;
  if (n > CAP) n = CAP;
  for (int i = tid; i < SHIST; i += 256) hist[i] = 0;
  if (tid == 0) sh_nfin = 0;
  __syncthreads();
  // level 1: top-12 key bits
  for (int i = tid; i < n; i += 256)
    atomicAdd(&hist[(unsigned)(cand_g[i] >> 52)], 1u);
  __syncthreads();
  suffix_thresh(hist, seg, (unsigned)K, &sh_bin, &sh_above, tid);
  int tbin = sh_bin;
  unsigned cnt_hi = sh_above;          // count with bin > tbin (< K)
  __syncthreads();
  // level 2: bits [19:8] within the tie bin
  for (int i = tid; i < SHIST; i += 256) hist[i] = 0;
  __syncthreads();
  for (int i = tid; i < n; i += 256) {
    unsigned key = (unsigned)(cand_g[i] >> 32);
    if ((int)(key >> 20) == tbin) atomicAdd(&hist[(key >> 8) & 0xFFFu], 1u);
  }
  __syncthreads();
  unsigned need = (unsigned)K - cnt_hi;
  suffix_thresh(hist, seg, need, &sh_bin, &sh_above, tid);
  int tbin2 = sh_bin;
  __syncthreads();
  // collect finalists
  for (int i = tid; i < n; i += 256) {
    u64 c = cand_g[i];
    unsigned key = (unsigned)(c >> 32);
    int bin = (int)(key >> 20);
    bool keep = (bin > tbin) || (bin == tbin && (int)((key >> 8) & 0xFFFu) >= tbin2);
    if (keep) {
      int p = atomicAdd(&sh_nfin, 1);
      if (p < FINCAP) fin[p] = c;
    }
  }
  __syncthreads();
  int nf = sh_nfin < FINCAP ? sh_nfin : FINCAP;
  int m = 2;
  while (m < nf) m <<= 1;              // power of two <= FINCAP
  for (int i = nf + tid; i < m; i += 256) fin[i] = 0ull;
  __syncthreads();
  for (int k2 = 2; k2 <= m; k2 <<= 1) {
    for (int j = k2 >> 1; j > 0; j >>= 1) {
      for (int i = tid; i < m; i += 256) {
        int l = i ^ j;
        if (l > i) {
          u64 ai = fin[i], al = fin[l];
          bool desc = ((i & k2) == 0);
          if (desc ? (ai < al) : (ai > al)) { fin[i] = al; fin[l] = ai; }
        }
      }
      __syncthreads();
    }
  }
  if (tid < K) {
    u64 c = fin[tid];
    unsigned key = (unsigned)(c >> 32);
    unsigned flat = 0xFFFFFFFFu - (unsigned)(c & 0xFFFFFFFFull);
    int b = (int)(flat / (unsigned)V);
    int v = (int)(flat - (unsigned)b * (unsigned)V);
    out_sum[tid] = key2f(key);         // bit-exact sum[b] + penalized lp
    qsel[tid] = b;
    tok[tid] = v;
    float x = logp[(size_t)b * V + v];
    if (v == V - 1) x -= 1000.0f;
    loc[tid] = x;                      // exact ys value
  }
}

extern "C" __global__ void __launch_bounds__(256)
k_scatter(const int* __restrict__ beam_seq, const float* __restrict__ beam_lp,
          const float4* __restrict__ h4, const float4* __restrict__ c4,
          const int* __restrict__ tptr, const int* __restrict__ qsel,
          const int* __restrict__ tok, const float* __restrict__ loc,
          int T, int B, int LBH4, int H4,
          float* __restrict__ out, float4* __restrict__ outh4,
          float4* __restrict__ outc4) {
  int t = *tptr;
  size_t n_seq = (size_t)T * B;
  size_t scalar_items = 2 * n_seq;
  size_t total = scalar_items + 2 * (size_t)LBH4;
  size_t stride = (size_t)gridDim.x * 256;
  for (size_t j = (size_t)blockIdx.x * 256 + threadIdx.x; j < total; j += stride) {
    if (j < n_seq) {
      int ss = (int)(j / B), b = (int)(j % B);
      int val;
      if (ss < t)       val = beam_seq[(size_t)ss * B + qsel[b]];
      else if (ss == t) val = tok[b];
      else              val = beam_seq[j];
      out[j] = (float)val;             // token ids < 2^24: exact in f32
    } else if (j < scalar_items) {
      size_t jj = j - n_seq;
      int ss = (int)(jj / B), b = (int)(jj % B);
      float v;
      if (ss < t)       v = beam_lp[(size_t)ss * B + qsel[b]];
      else if (ss == t) v = loc[b];
      else              v = beam_lp[jj];
      out[j] = v;
    } else {
      size_t jj = j - scalar_items;
      bool is_c = jj >= (size_t)LBH4;
      size_t k = is_c ? jj - (size_t)LBH4 : jj;
      int row = (int)(k / H4);
      int h = (int)(k - (size_t)row * H4);
      int b = row % B;                 // row = l*B + b
      size_t src = (size_t)(row - b + qsel[b]) * H4 + h;
      if (is_c) outc4[k] = c4[src];
      else      outh4[k] = h4[src];
    }
  }
}

extern "C" void kernel_launch(void* const* d_in, const int* in_sizes, int n_in,
                              void* d_out, int out_size, void* d_ws, size_t ws_size,
                              hipStream_t stream) {
  const float* logp = (const float*)d_in[0];
  const int* beam_seq = (const int*)d_in[1];
  const float* beam_lp = (const float*)d_in[2];
  const float* bsum = (const float*)d_in[3];
  const float* st_h = (const float*)d_in[4];
  const float* st_c = (const float*)d_in[5];
  const int* tptr = (const int*)d_in[6];

  int B = in_sizes[3];                 // 128
  int V = in_sizes[0] / B;             // 128000
  int T = in_sizes[1] / B;             // 128
  int LBH = in_sizes[4];               // L*B*H = 262144
  int LH = LBH / B;                    // L*H = 2048
  int bs = (out_size - 2 * in_sizes[1]) / (1 + 2 * LH);  // beam_size = 128
  int H = 1024;                        // fixed for this problem
  int H4 = H / 4, LBH4 = LBH / 4;

  char* ws = (char*)d_ws;
  unsigned* shist = (unsigned*)ws;                        // 16384 B
  int* cnt = (int*)(ws + 16384);                          // 4 B
  unsigned* tlo_key = (unsigned*)(ws + 16388);            // 4 B
  u64* cand = (u64*)(ws + 16392);                         // CAP*8 B (8-aligned)
  int* qsel = (int*)(ws + 16392 + CAP * 8);
  int* tok = qsel + bs;
  float* loc = (float*)(tok + bs);

  float* out = (float*)d_out;
  size_t n_seq = (size_t)T * B;
  float* out_sum = out + 2 * n_seq;
  float4* outh4 = (float4*)(out + 2 * n_seq + bs);        // 16B-aligned offset
  float4* outc4 = outh4 + LBH4;

  hipMemsetAsync(d_ws, 0, 16392, stream);
  k_sample<<<256, 256, 0, stream>>>(logp, bsum, tptr, V, bs, shist);
  k_pick<<<1, 256, 0, stream>>>(shist, bs, tlo_key);
  k_main<<<1024, 256, 0, stream>>>(logp, bsum, tptr, V, bs, tlo_key, cand, cnt);
  k_select<<<1, 256, 0, stream>>>(logp, cnt, cand, V, bs, out_sum, qsel, tok, loc);

  size_t total = 2 * n_seq + 2 * (size_t)LBH4;
  int blocks = (int)((total + 255) / 256);
  k_scatter<<<blocks, 256, 0, stream>>>(beam_seq, beam_lp,
                                        (const float4*)st_h, (const float4*)st_c,
                                        tptr, qsel, tok, loc,
                                        T, B, LBH4, H4, out, outh4, outc4);
}